// Round 1
// baseline (131.704 us; speedup 1.0000x reference)
//
#include <hip/hip_runtime.h>
#include <math.h>

// Problem constants (match reference)
#define BB 2048      // batch rows
#define TT 8192      // time steps
#define CC 128       // chunks
#define LL 64        // steps per chunk (CC*LL = TT, step t=8192 is a zero-pad no-op)

// Workspace layout (bytes):
//   coef4 : float4[8256]          @ 0        (132096 B)  (m, b, p, w) per t; t in [8192,8256) zeroed
//   A4    : float4[128]           @ 132096   (2048 B)    per-chunk composed (alpha,beta,gamma,delta)
//   Wsum  : float [128]           @ 134144   (512 B)     per-chunk sum of w
//   Q1/Q2/Q3 : float[128*2048] ea @ 135168   (3 MiB)     per-(chunk,row) local outputs
#define OFF_A4    132096
#define OFF_WSUM  134144
#define OFF_Q     135168

__device__ inline float sigmoid_dev(float v) {
    return 1.0f / (1.0f + expf(-v));
}

__device__ inline float squash_dev(float v, float lo, float hi) {
    return lo + (hi - lo) * sigmoid_dev(v);
}

struct SquashedParams {
    float c, f_start, f_inf, log2K_invTd, w_offset, w_T;
};

__device__ inline SquashedParams load_params(const int* Fp,
                                             const float* p_fstart, const float* p_finf,
                                             const float* p_fdecay, const float* p_fT,
                                             const float* p_woff, const float* p_wT) {
    SquashedParams P;
    float Fv       = (float)(*Fp);
    P.c            = sqrtf(exp2f(1.0f / 3.0f) - 1.0f) * Fv / 3.14159265358979323846f;
    P.f_start      = squash_dev(*p_fstart, 200.0f, 4000.0f);
    P.f_inf        = squash_dev(*p_finf,   20.0f,  500.0f);
    float f_decay  = squash_dev(*p_fdecay, 0.0f,   2.0f);
    float f_T      = squash_dev(*p_fT,     0.0f,   2.0f);
    P.w_offset     = squash_dev(*p_woff,   0.0f,   1.0f);
    P.w_T          = squash_dev(*p_wT,     0.01f,  0.5f);
    // f(t) = f_inf + (f_start - f_inf) * exp2( log2K_invTd * (t/TT) )
    const float LOG2_10 = 3.32192809488736235f;
    float log2K  = log2f(0.7f) - LOG2_10 * f_decay;       // log2(0.7 * 0.1^f_decay)
    float invTd  = 0.1f * exp2f(LOG2_10 * f_T);           // 1 / (10 * 0.1^f_T)
    P.log2K_invTd = log2K * invTd;
    return P;
}

// Kernel 1a: per-t coefficients (m, b, p, w), zero-padded for t in [TT, TT+LL)
__global__ void coef_kernel(const int* Fp,
                            const float* p_fstart, const float* p_finf,
                            const float* p_fdecay, const float* p_fT,
                            const float* p_woff, const float* p_wT,
                            float4* __restrict__ coef) {
    int t = blockIdx.x * blockDim.x + threadIdx.x;
    if (t >= TT + LL) return;
    float4 cf;
    if (t >= TT) {
        cf = make_float4(0.0f, 0.0f, 0.0f, 0.0f);
    } else {
        SquashedParams P = load_params(Fp, p_fstart, p_finf, p_fdecay, p_fT, p_woff, p_wT);
        float ti = (float)t * (1.0f / (float)TT);
        float f  = P.f_inf + (P.f_start - P.f_inf) * exp2f(P.log2K_invTd * ti);
        float a  = (f - P.c) / (f + P.c);
        float b  = 0.5f * (a + 1.0f);
        float m  = -a;
        float p  = b * (1.0f + m);
        float z  = (ti - P.w_offset) / P.w_T;
        z        = fminf(fmaxf(z, -60.0f), 60.0f);
        float w  = 1.0f / (1.0f + expf(-z));
        cf = make_float4(m, b, p, w);
    }
    coef[t] = cf;
}

// Kernel 1b: compose per-chunk transition A_j = (alpha,beta,gamma,delta) + per-chunk sum(w)
// Step matrix on (y1,y2,acc): [[m,0,0],[p,m,0],[w*p,w*m,1]]
__global__ void chunkmat_kernel(const float4* __restrict__ coef,
                                float4* __restrict__ A4, float* __restrict__ Wsum) {
    int j = threadIdx.x;   // 0..CC-1, single block
    if (j >= CC) return;
    const float4* cf = coef + 1 + j * LL;
    float al = 1.0f, be = 0.0f, ga = 0.0f, de = 0.0f, ws = 0.0f;
    #pragma unroll 8
    for (int k = 0; k < LL; k++) {
        float4 c4 = cf[k];
        float m = c4.x, p = c4.z, w = c4.w;
        float nal = m * al;
        float nbe = fmaf(p, al, m * be);
        de = fmaf(w * m, al, de);
        ga = fmaf(w, nbe, ga);
        al = nal; be = nbe;
        ws += w;
    }
    A4[j] = make_float4(al, be, ga, de);
    Wsum[j] = ws;
}

// Kernel 2: per-(row,chunk) local run from zero state -> q = (y1, y2, acc)
// grid: CC*8 blocks of 256; block -> (chunk j, 256 consecutive rows)
__global__ void chunk_kernel(const float* __restrict__ X, const float4* __restrict__ coef,
                             float* __restrict__ Q1, float* __restrict__ Q2,
                             float* __restrict__ Q3) {
    int j = blockIdx.x >> 3;                         // chunk (wave-uniform)
    int b = ((blockIdx.x & 7) << 8) + threadIdx.x;   // row

    __shared__ float4 sc[LL];
    if (threadIdx.x < LL) sc[threadIdx.x] = coef[1 + j * LL + threadIdx.x];
    __syncthreads();

    const float* base = X + (size_t)b * TT + j * LL;   // 256-B aligned
    float e[LL];
    #pragma unroll
    for (int i = 0; i < LL / 4; i++) {
        float4 v = reinterpret_cast<const float4*>(base)[i];
        e[4 * i + 0] = v.x; e[4 * i + 1] = v.y;
        e[4 * i + 2] = v.z; e[4 * i + 3] = v.w;
    }
    float e_next = (j < CC - 1) ? base[LL] : 0.0f;   // first x of next chunk (pad step if j==CC-1)

    float y1 = 0.0f, y2 = 0.0f, acc = 0.0f;
    #pragma unroll
    for (int k = 0; k < LL; k++) {
        float4 c4 = sc[k];                       // (m, b, p, w) — wave-uniform broadcast
        float x  = (k < LL - 1) ? e[k + 1] : e_next;
        float xp = e[k];
        float u  = c4.y * (x + xp);              // b*(x_t + x_{t-1})
        float y2n = fmaf(c4.x, y2, fmaf(c4.z, y1, c4.y * u));  // m*y2 + p*y1 + b*u
        y1 = fmaf(c4.x, y1, u);                  // m*y1 + u
        y2 = y2n;
        acc = fmaf(c4.w, y2n, acc);              // += w*y2
    }
    int idx = j * BB + b;                        // [chunk][row] -> coalesced store
    Q1[idx] = y1; Q2[idx] = y2; Q3[idx] = acc;
}

// Kernel 3: per-row fold over chunks: s <- A_j * s + q_j ; out = acc / sum(w)
__global__ void combine_kernel(const float* __restrict__ X, const float4* __restrict__ coef,
                               const float4* __restrict__ A4, const float* __restrict__ Wsum,
                               const float* __restrict__ Q1, const float* __restrict__ Q2,
                               const float* __restrict__ Q3, float* __restrict__ out) {
    int b = blockIdx.x * blockDim.x + threadIdx.x;   // row
    float x0 = X[(size_t)b * TT];
    float w0 = coef[0].w;                            // wave-uniform
    float y1 = x0, y2 = x0, acc = w0 * x0, sumw = w0;
    for (int j = 0; j < CC; j++) {
        float4 A = A4[j];                            // (alpha,beta,gamma,delta) uniform
        int idx = j * BB + b;
        float q1 = Q1[idx], q2 = Q2[idx], q3 = Q3[idx];
        float ny1 = fmaf(A.x, y1, q1);
        float ny2 = fmaf(A.x, y2, fmaf(A.y, y1, q2));
        acc += fmaf(A.z, y1, fmaf(A.w, y2, q3));
        sumw += Wsum[j];
        y1 = ny1; y2 = ny2;
    }
    out[b] = acc / sumw;
}

extern "C" void kernel_launch(void* const* d_in, const int* in_sizes, int n_in,
                              void* d_out, int out_size, void* d_ws, size_t ws_size,
                              hipStream_t stream) {
    const float* X        = (const float*)d_in[0];
    const int*   Fp       = (const int*)d_in[1];
    const float* p_fstart = (const float*)d_in[2];
    const float* p_finf   = (const float*)d_in[3];
    const float* p_fdecay = (const float*)d_in[4];
    const float* p_fT     = (const float*)d_in[5];
    const float* p_woff   = (const float*)d_in[6];
    const float* p_wT     = (const float*)d_in[7];
    float* out = (float*)d_out;

    char* ws = (char*)d_ws;
    float4* coef = (float4*)ws;
    float4* A4   = (float4*)(ws + OFF_A4);
    float*  Wsum = (float*)(ws + OFF_WSUM);
    float*  Q1   = (float*)(ws + OFF_Q);
    float*  Q2   = Q1 + CC * BB;
    float*  Q3   = Q2 + CC * BB;

    // 1a: coefficients (8256 entries incl. pad)
    coef_kernel<<<(TT + LL + 255) / 256, 256, 0, stream>>>(
        Fp, p_fstart, p_finf, p_fdecay, p_fT, p_woff, p_wT, coef);
    // 1b: per-chunk transition matrices
    chunkmat_kernel<<<1, CC, 0, stream>>>(coef, A4, Wsum);
    // 2: per-(row,chunk) local scans
    chunk_kernel<<<CC * 8, 256, 0, stream>>>(X, coef, Q1, Q2, Q3);
    // 3: per-row cross-chunk combine
    combine_kernel<<<BB / 256, 256, 0, stream>>>(X, coef, A4, Wsum, Q1, Q2, Q3, out);
}

// Round 2
// 124.726 us; speedup vs baseline: 1.0559x; 1.0559x over previous
//
#include <hip/hip_runtime.h>
#include <math.h>

// Problem constants (match reference)
#define BB 2048      // batch rows
#define TT 8192      // time steps
#define CC 128       // chunks
#define LL 64        // steps per chunk (CC*LL = TT; global step t = 1 + j*LL + k, k=63@j=127 is zero-pad)

// Workspace layout (bytes):
//   A4 : float4[128]        @ 0      per-chunk composed (alpha,beta,gamma,delta)
//   SC : float[2]           @ 2048   {1/sum(w), w0}
//   Q4 : float4[CC*BB]      @ 4096   per-(chunk,row) local outputs (y1,y2,acc,unused)
#define OFF_SC  2048
#define OFF_Q   4096

__device__ inline float sigmoid_dev(float v) { return 1.0f / (1.0f + expf(-v)); }
__device__ inline float squash_dev(float v, float lo, float hi) {
    return lo + (hi - lo) * sigmoid_dev(v);
}

struct SquashedParams {
    float c, f_start, f_inf, log2K_invTd, w_offset, inv_w_T;
};

__device__ inline SquashedParams load_params(const int* Fp,
                                             const float* p_fstart, const float* p_finf,
                                             const float* p_fdecay, const float* p_fT,
                                             const float* p_woff, const float* p_wT) {
    SquashedParams P;
    float Fv      = (float)(*Fp);
    P.c           = sqrtf(exp2f(1.0f / 3.0f) - 1.0f) * Fv / 3.14159265358979323846f;
    P.f_start     = squash_dev(*p_fstart, 200.0f, 4000.0f);
    P.f_inf       = squash_dev(*p_finf,   20.0f,  500.0f);
    float f_decay = squash_dev(*p_fdecay, 0.0f,   2.0f);
    float f_T     = squash_dev(*p_fT,     0.0f,   2.0f);
    P.w_offset    = squash_dev(*p_woff,   0.0f,   1.0f);
    float w_T     = squash_dev(*p_wT,     0.01f,  0.5f);
    P.inv_w_T     = 1.0f / w_T;
    const float LOG2_10 = 3.32192809488736235f;
    float log2K  = log2f(0.7f) - LOG2_10 * f_decay;   // log2(0.7 * 0.1^f_decay)
    float invTd  = 0.1f * exp2f(LOG2_10 * f_T);       // 1 / (10 * 0.1^f_T)
    P.log2K_invTd = log2K * invTd;
    return P;
}

// (m, b, p, w) for global step t = tg+1, where tg in [0, TT-1); tg >= TT-1 is the zero pad
__device__ inline float4 step_coef(const SquashedParams& P, int tg) {
    if (tg >= TT - 1) return make_float4(0.0f, 0.0f, 0.0f, 0.0f);
    float ti = (float)(tg + 1) * (1.0f / (float)TT);
    float f  = P.f_inf + (P.f_start - P.f_inf) * exp2f(P.log2K_invTd * ti);
    float a  = (f - P.c) / (f + P.c);
    float b  = 0.5f * (a + 1.0f);
    float m  = -a;
    float p  = b * (1.0f + m);
    float w  = sigmoid_dev((ti - P.w_offset) * P.inv_w_T);
    return make_float4(m, b, p, w);
}

// K1: one block, 128 threads. Thread j composes chunk j's 64 step matrices into A_j;
// block-reduces sum(w); thread 0 writes SC = {1/sumw_total, w0}.
__global__ void setup_kernel(const int* Fp,
                             const float* p_fstart, const float* p_finf,
                             const float* p_fdecay, const float* p_fT,
                             const float* p_woff, const float* p_wT,
                             float4* __restrict__ A4, float* __restrict__ SC) {
    int j = threadIdx.x;   // chunk
    SquashedParams P = load_params(Fp, p_fstart, p_finf, p_fdecay, p_fT, p_woff, p_wT);
    float al = 1.0f, be = 0.0f, ga = 0.0f, de = 0.0f, ws = 0.0f;
    for (int k = 0; k < LL; k++) {
        float4 c4 = step_coef(P, j * LL + k);
        float m = c4.x, p = c4.z, w = c4.w;
        float nal = m * al;
        float nbe = fmaf(p, al, m * be);
        de = fmaf(w * m, al, de);
        ga = fmaf(w, nbe, ga);
        al = nal; be = nbe;
        ws += w;
    }
    A4[j] = make_float4(al, be, ga, de);

    __shared__ float sws[CC];
    sws[j] = ws;
    __syncthreads();
    for (int s = CC / 2; s > 0; s >>= 1) {
        if (j < s) sws[j] += sws[j + s];
        __syncthreads();
    }
    if (j == 0) {
        float w0 = sigmoid_dev((0.0f - P.w_offset) * P.inv_w_T);
        float tot = w0 + sws[0];
        SC[0] = 1.0f / tot;
        SC[1] = w0;
    }
}

// K2: per-(row,chunk) local scan from zero state -> (y1, y2, acc).
// grid: CC*8 blocks of 256; block -> (chunk j, 256 consecutive rows).
// Threads 0..63 compute the chunk's coefficients into LDS first.
__global__ void chunk_kernel(const float* __restrict__ X,
                             const int* Fp,
                             const float* p_fstart, const float* p_finf,
                             const float* p_fdecay, const float* p_fT,
                             const float* p_woff, const float* p_wT,
                             float4* __restrict__ Q4) {
    int j = blockIdx.x >> 3;                         // chunk (wave-uniform)
    int b = ((blockIdx.x & 7) << 8) + threadIdx.x;   // row

    __shared__ float4 sc[LL];
    if (threadIdx.x < LL) {
        SquashedParams P = load_params(Fp, p_fstart, p_finf, p_fdecay, p_fT, p_woff, p_wT);
        sc[threadIdx.x] = step_coef(P, j * LL + threadIdx.x);
    }
    __syncthreads();

    const float* base = X + (size_t)b * TT + j * LL;   // 256-B aligned
    float e[LL];
    #pragma unroll
    for (int i = 0; i < LL / 4; i++) {
        float4 v = reinterpret_cast<const float4*>(base)[i];
        e[4 * i + 0] = v.x; e[4 * i + 1] = v.y;
        e[4 * i + 2] = v.z; e[4 * i + 3] = v.w;
    }
    float e_next = (j < CC - 1) ? base[LL] : 0.0f;   // x for the (padded) last step of chunk 127

    float y1 = 0.0f, y2 = 0.0f, acc = 0.0f;
    #pragma unroll
    for (int k = 0; k < LL; k++) {
        float4 c4 = sc[k];                       // (m, b, p, w) — wave-uniform broadcast
        float x  = (k < LL - 1) ? e[k + 1] : e_next;
        float xp = e[k];
        float u  = c4.y * (x + xp);              // b*(x_t + x_{t-1})
        float y2n = fmaf(c4.x, y2, fmaf(c4.z, y1, c4.y * u));  // m*y2 + p*y1 + b*u
        y1 = fmaf(c4.x, y1, u);                  // m*y1 + u
        y2 = y2n;
        acc = fmaf(c4.w, y2n, acc);              // += w*y2
    }
    Q4[j * BB + b] = make_float4(y1, y2, acc, 0.0f);   // [chunk][row] -> coalesced b128 store
}

// K3: one wave per row; lane L composes chunks 2L and 2L+1, then a 6-step shfl_down
// composition tree; lane 0 applies the full map to s0 = (x0, x0, w0*x0).
// Map h = (al,be,ga,de,q1,q2,q3):
//   y1' = al*y1 + q1;  y2' = be*y1 + al*y2 + q2;  acc' = ga*y1 + de*y2 + acc + q3
__global__ void combine_kernel(const float* __restrict__ X,
                               const float4* __restrict__ A4, const float* __restrict__ SC,
                               const float4* __restrict__ Q4, float* __restrict__ out) {
    int wid  = threadIdx.x >> 6;
    int lane = threadIdx.x & 63;
    int r    = (blockIdx.x << 2) + wid;              // row
    int c0   = lane << 1;                            // first of this lane's two chunks

    float x0 = X[(size_t)r * TT];                    // issue early (wave-uniform line)
    float4 Aa = A4[c0], Ab = A4[c0 + 1];
    float4 qa = Q4[(size_t)c0 * BB + r];
    float4 qb = Q4[(size_t)(c0 + 1) * BB + r];

    // T = T_b (later) ∘ T_a (earlier)
    float al = Ab.x * Aa.x;
    float be = fmaf(Ab.y, Aa.x, Ab.x * Aa.y);
    float ga = fmaf(Ab.z, Aa.x, fmaf(Ab.w, Aa.y, Aa.z));
    float de = fmaf(Ab.w, Aa.x, Aa.w);
    float q1 = fmaf(Ab.x, qa.x, qb.x);
    float q2 = fmaf(Ab.y, qa.x, fmaf(Ab.x, qa.y, qb.y));
    float q3 = fmaf(Ab.z, qa.x, fmaf(Ab.w, qa.y, qa.z + qb.z));

    #pragma unroll
    for (int o = 1; o < 64; o <<= 1) {
        float al2 = __shfl_down(al, o);
        float be2 = __shfl_down(be, o);
        float ga2 = __shfl_down(ga, o);
        float de2 = __shfl_down(de, o);
        float q12 = __shfl_down(q1, o);
        float q22 = __shfl_down(q2, o);
        float q32 = __shfl_down(q3, o);
        // T <- T2 (later) ∘ T (earlier)
        float nal = al2 * al;
        float nbe = fmaf(be2, al, al2 * be);
        float nga = fmaf(ga2, al, fmaf(de2, be, ga));
        float nde = fmaf(de2, al, de);
        float nq1 = fmaf(al2, q1, q12);
        float nq2 = fmaf(be2, q1, fmaf(al2, q2, q22));
        float nq3 = fmaf(ga2, q1, fmaf(de2, q2, q3 + q32));
        al = nal; be = nbe; ga = nga; de = nde; q1 = nq1; q2 = nq2; q3 = nq3;
    }

    if (lane == 0) {
        float w0 = SC[1];
        float accf = fmaf(ga + de + w0, x0, q3);     // (ga+de)*x0 + w0*x0 + q3
        out[r] = accf * SC[0];
    }
}

extern "C" void kernel_launch(void* const* d_in, const int* in_sizes, int n_in,
                              void* d_out, int out_size, void* d_ws, size_t ws_size,
                              hipStream_t stream) {
    const float* X        = (const float*)d_in[0];
    const int*   Fp       = (const int*)d_in[1];
    const float* p_fstart = (const float*)d_in[2];
    const float* p_finf   = (const float*)d_in[3];
    const float* p_fdecay = (const float*)d_in[4];
    const float* p_fT     = (const float*)d_in[5];
    const float* p_woff   = (const float*)d_in[6];
    const float* p_wT     = (const float*)d_in[7];
    float* out = (float*)d_out;

    char* ws = (char*)d_ws;
    float4* A4 = (float4*)ws;
    float*  SC = (float*)(ws + OFF_SC);
    float4* Q4 = (float4*)(ws + OFF_Q);

    setup_kernel<<<1, CC, 0, stream>>>(Fp, p_fstart, p_finf, p_fdecay, p_fT,
                                       p_woff, p_wT, A4, SC);
    chunk_kernel<<<CC * 8, 256, 0, stream>>>(X, Fp, p_fstart, p_finf, p_fdecay,
                                             p_fT, p_woff, p_wT, Q4);
    combine_kernel<<<BB / 4, 256, 0, stream>>>(X, A4, SC, Q4, out);
}

// Round 3
// 121.879 us; speedup vs baseline: 1.0806x; 1.0234x over previous
//
#include <hip/hip_runtime.h>
#include <math.h>

// Problem constants (match reference)
#define BB 2048      // batch rows
#define TT 8192      // time steps
#define NSEG 128     // segments per row
#define SL 64        // steps per segment (NSEG*SL = TT; global step t = 1+seg*SL+k; t=8192 is zero-pad)

__device__ inline float sigmoid_dev(float v) { return 1.0f / (1.0f + __expf(-v)); }
__device__ inline float squash_dev(float v, float lo, float hi) {
    return lo + (hi - lo) * sigmoid_dev(v);
}

struct SquashedParams {
    float c, f_start, f_inf, log2K_invTd, w_offset, inv_w_T;
};

__device__ inline SquashedParams load_params(const int* Fp,
                                             const float* p_fstart, const float* p_finf,
                                             const float* p_fdecay, const float* p_fT,
                                             const float* p_woff, const float* p_wT) {
    SquashedParams P;
    float Fv      = (float)(*Fp);
    P.c           = sqrtf(exp2f(1.0f / 3.0f) - 1.0f) * Fv / 3.14159265358979323846f;
    P.f_start     = squash_dev(*p_fstart, 200.0f, 4000.0f);
    P.f_inf       = squash_dev(*p_finf,   20.0f,  500.0f);
    float f_decay = squash_dev(*p_fdecay, 0.0f,   2.0f);
    float f_T     = squash_dev(*p_fT,     0.0f,   2.0f);
    P.w_offset    = squash_dev(*p_woff,   0.0f,   1.0f);
    float w_T     = squash_dev(*p_wT,     0.01f,  0.5f);
    P.inv_w_T     = 1.0f / w_T;
    const float LOG2_10 = 3.32192809488736235f;
    float log2K  = log2f(0.7f) - LOG2_10 * f_decay;   // log2(0.7 * 0.1^f_decay)
    float invTd  = 0.1f * exp2f(LOG2_10 * f_T);       // 1 / (10 * 0.1^f_T)
    P.log2K_invTd = log2K * invTd;
    return P;
}

// Fully fused: one wave = one half-row (64 segments of 64 steps).
// Lane = one segment: local scan from zero state (q1,q2,q3) + composed transition
// (al,be,ga,de) + sum(w), coefficients computed inline. Then a 6-step shfl
// composition tree per wave, a 2-wave LDS combine per row, apply to
// s0=(x0,x0,w0*x0), divide by total sum(w).
//
// Affine map h = (al,be,ga,de | q1,q2,q3):
//   y1' = al*y1 + q1
//   y2' = be*y1 + al*y2 + q2
//   acc' = ga*y1 + de*y2 + acc + q3
// Per-step matrix on (y1,y2,acc): [[m,0,0],[p,m,0],[w*p,w*m,1]], u-feed via q.
__global__ __launch_bounds__(256, 4)
void fused_kernel(const float* __restrict__ X,
                  const int* Fp,
                  const float* p_fstart, const float* p_finf,
                  const float* p_fdecay, const float* p_fT,
                  const float* p_woff, const float* p_wT,
                  float* __restrict__ out) {
    const int tid  = threadIdx.x;
    const int lane = tid & 63;
    const int wid  = tid >> 6;          // 0..3
    const int rloc = wid >> 1;          // 0..1  local row
    const int half = wid & 1;           // 0 = segments 0..63, 1 = segments 64..127
    const int row  = (blockIdx.x << 1) + rloc;
    const int seg  = (half << 6) + lane;

    SquashedParams P = load_params(Fp, p_fstart, p_finf, p_fdecay, p_fT, p_woff, p_wT);

    // ---- load this lane's 64 input samples (16 b128, contiguous 16 KB per wave) ----
    const float* base = X + (size_t)row * TT + seg * SL;   // 256-B aligned
    float e[SL];
    #pragma unroll
    for (int i = 0; i < SL / 4; i++) {
        float4 v = reinterpret_cast<const float4*>(base)[i];
        e[4 * i + 0] = v.x; e[4 * i + 1] = v.y;
        e[4 * i + 2] = v.z; e[4 * i + 3] = v.w;
    }
    float xn = 0.0f;
    if (seg < NSEG - 1) xn = base[SL];   // x for this segment's last step (line already fetched)

    // ---- 64-step local scan + transition composition, coefs inline ----
    const float dti     = 1.0f / (float)TT;
    const float ti_base = (float)(seg * SL + 1) * dti;
    const float df      = P.f_start - P.f_inf;

    float y1 = 0.0f, y2 = 0.0f, q3 = 0.0f;
    float al = 1.0f, be = 0.0f, ga = 0.0f, de = 0.0f, ws = 0.0f;
    #pragma unroll
    for (int k = 0; k < SL; k++) {
        float ti = fmaf((float)k, dti, ti_base);
        float f  = fmaf(df, exp2f(P.log2K_invTd * ti), P.f_inf);
        float r  = 1.0f / (f + P.c);
        float b  = f * r;                 // (a+1)/2
        float m  = (P.c - f) * r;         // -a
        float p  = b * (1.0f + m);
        float w  = sigmoid_dev((ti - P.w_offset) * P.inv_w_T);
        if (seg == NSEG - 1 && k == SL - 1) { m = 0.0f; b = 0.0f; p = 0.0f; w = 0.0f; } // t=8192 pad

        float x  = (k < SL - 1) ? e[k + 1] : xn;
        float u  = b * (x + e[k]);                              // b*(x_t + x_{t-1})
        float y2n = fmaf(m, y2, fmaf(p, y1, b * u));            // m*y2 + p*y1 + b*u
        y1 = fmaf(m, y1, u);
        y2 = y2n;
        q3 = fmaf(w, y2n, q3);                                  // local acc

        float nal = m * al;
        float nbe = fmaf(p, al, m * be);
        de = fmaf(w * m, al, de);
        ga = fmaf(w, nbe, ga);
        al = nal; be = nbe;
        ws += w;
    }
    float q1 = y1, q2 = y2;

    // ---- in-wave composition tree: lane 0 ends with the half-row map ----
    #pragma unroll
    for (int o = 1; o < 64; o <<= 1) {
        float al2 = __shfl_down(al, o);
        float be2 = __shfl_down(be, o);
        float ga2 = __shfl_down(ga, o);
        float de2 = __shfl_down(de, o);
        float q12 = __shfl_down(q1, o);
        float q22 = __shfl_down(q2, o);
        float q32 = __shfl_down(q3, o);
        float ws2 = __shfl_down(ws, o);
        // T <- T2 (later) ∘ T (earlier)
        float nal = al2 * al;
        float nbe = fmaf(be2, al, al2 * be);
        float nga = fmaf(ga2, al, fmaf(de2, be, ga));
        float nde = fmaf(de2, al, de);
        float nq1 = fmaf(al2, q1, q12);
        float nq2 = fmaf(be2, q1, fmaf(al2, q2, q22));
        float nq3 = fmaf(ga2, q1, fmaf(de2, q2, q3 + q32));
        al = nal; be = nbe; ga = nga; de = nde;
        q1 = nq1; q2 = nq2; q3 = nq3; ws += ws2;
    }

    // ---- cross-wave (2 halves) combine per row ----
    __shared__ float sred[4][8];   // per wave: al,be,ga,de,q1,q2,q3,ws
    __shared__ float sx0[2];       // per local row: X[row][0]
    if (lane == 0) {
        sred[wid][0] = al; sred[wid][1] = be; sred[wid][2] = ga; sred[wid][3] = de;
        sred[wid][4] = q1; sred[wid][5] = q2; sred[wid][6] = q3; sred[wid][7] = ws;
        if (half == 0) sx0[rloc] = e[0];     // seg 0 starts at X[row][0]
    }
    __syncthreads();

    if (tid < 2) {
        int r = tid;
        const float* E = sred[2 * r + 0];    // earlier half (segments 0..63)
        const float* L = sred[2 * r + 1];    // later half (segments 64..127)
        float alE = E[0], beE = E[1], gaE = E[2], deE = E[3];
        float q1E = E[4], q2E = E[5], q3E = E[6];
        float gaL = L[2], deL = L[3], q3L = L[6];
        // acc row of T_L ∘ T_E applied to s0, plus q-feeds:
        float ga_f = fmaf(gaL, alE, fmaf(deL, beE, gaE));
        float de_f = fmaf(deL, alE, deE);
        float q3_f = fmaf(gaL, q1E, fmaf(deL, q2E, q3E + q3L));
        float x0 = sx0[r];
        float w0 = sigmoid_dev((0.0f - P.w_offset) * P.inv_w_T);
        float sumw = E[7] + L[7] + w0;
        float accf = fmaf(ga_f + de_f + w0, x0, q3_f);
        out[(blockIdx.x << 1) + r] = accf / sumw;
    }
}

extern "C" void kernel_launch(void* const* d_in, const int* in_sizes, int n_in,
                              void* d_out, int out_size, void* d_ws, size_t ws_size,
                              hipStream_t stream) {
    const float* X        = (const float*)d_in[0];
    const int*   Fp       = (const int*)d_in[1];
    const float* p_fstart = (const float*)d_in[2];
    const float* p_finf   = (const float*)d_in[3];
    const float* p_fdecay = (const float*)d_in[4];
    const float* p_fT     = (const float*)d_in[5];
    const float* p_woff   = (const float*)d_in[6];
    const float* p_wT     = (const float*)d_in[7];
    float* out = (float*)d_out;

    fused_kernel<<<BB / 2, 256, 0, stream>>>(X, Fp, p_fstart, p_finf, p_fdecay,
                                             p_fT, p_woff, p_wT, out);
}

// Round 4
// 108.517 us; speedup vs baseline: 1.2137x; 1.1231x over previous
//
#include <hip/hip_runtime.h>
#include <math.h>

// Problem constants (match reference)
#define BB 2048      // batch rows
#define TT 8192      // time steps
#define NSEG 128     // segments per row
#define SL 64        // steps per segment (NSEG*SL = TT; global step t = 1+seg*SL+k; t=8192 is zero-pad)

__device__ inline float sigmoid_dev(float v) { return 1.0f / (1.0f + __expf(-v)); }
__device__ inline float squash_dev(float v, float lo, float hi) {
    return lo + (hi - lo) * sigmoid_dev(v);
}

struct SquashedParams {
    float c, f_start, f_inf, log2K_invTd, w_offset, inv_w_T;
};

__device__ inline SquashedParams load_params(const int* Fp,
                                             const float* p_fstart, const float* p_finf,
                                             const float* p_fdecay, const float* p_fT,
                                             const float* p_woff, const float* p_wT) {
    SquashedParams P;
    float Fv      = (float)(*Fp);
    P.c           = sqrtf(exp2f(1.0f / 3.0f) - 1.0f) * Fv / 3.14159265358979323846f;
    P.f_start     = squash_dev(*p_fstart, 200.0f, 4000.0f);
    P.f_inf       = squash_dev(*p_finf,   20.0f,  500.0f);
    float f_decay = squash_dev(*p_fdecay, 0.0f,   2.0f);
    float f_T     = squash_dev(*p_fT,     0.0f,   2.0f);
    P.w_offset    = squash_dev(*p_woff,   0.0f,   1.0f);
    float w_T     = squash_dev(*p_wT,     0.01f,  0.5f);
    P.inv_w_T     = 1.0f / w_T;
    const float LOG2_10 = 3.32192809488736235f;
    float log2K  = log2f(0.7f) - LOG2_10 * f_decay;   // log2(0.7 * 0.1^f_decay)
    float invTd  = 0.1f * exp2f(LOG2_10 * f_T);       // 1 / (10 * 0.1^f_T)
    P.log2K_invTd = log2K * invTd;
    return P;
}

// Fully fused: one wave = one half-row (64 segments of 64 steps).
// Lane = one segment: local scan from zero state (q1,q2,q3) + composed transition
// (al,be,ga,de) + sum(w). Coefficients are GEOMETRIC in k, so the per-step
// exp2/exp/sigmoid collapse to two iterative multiplies (ef *= cf, ew *= cw)
// plus v_rcp — no transcendentals in the hot loop.
//
// Affine map h = (al,be,ga,de | q1,q2,q3):
//   y1' = al*y1 + q1
//   y2' = be*y1 + al*y2 + q2
//   acc' = ga*y1 + de*y2 + acc + q3
__global__ __launch_bounds__(256, 4)
void fused_kernel(const float* __restrict__ X,
                  const int* Fp,
                  const float* p_fstart, const float* p_finf,
                  const float* p_fdecay, const float* p_fT,
                  const float* p_woff, const float* p_wT,
                  float* __restrict__ out) {
    const int tid  = threadIdx.x;
    const int lane = tid & 63;
    const int wid  = tid >> 6;          // 0..3
    const int rloc = wid >> 1;          // 0..1  local row
    const int half = wid & 1;           // 0 = segments 0..63, 1 = segments 64..127
    const int row  = (blockIdx.x << 1) + rloc;
    const int seg  = (half << 6) + lane;

    SquashedParams P = load_params(Fp, p_fstart, p_finf, p_fdecay, p_fT, p_woff, p_wT);

    // ---- load this lane's 64 input samples (16 b128, contiguous 16 KB per wave) ----
    const float* base = X + (size_t)row * TT + seg * SL;   // 256-B aligned
    float e[SL];
    #pragma unroll
    for (int i = 0; i < SL / 4; i++) {
        float4 v = reinterpret_cast<const float4*>(base)[i];
        e[4 * i + 0] = v.x; e[4 * i + 1] = v.y;
        e[4 * i + 2] = v.z; e[4 * i + 3] = v.w;
    }
    // x for this segment's last step = first sample of the next segment.
    // Lanes 0..62: neighbor lane's e[0]. Lane 63: one global load (line shared
    // with the next wave's fetch; seg==127 is the zero-pad step, value unused).
    float xn = __shfl_down(e[0], 1);
    if (lane == 63 && seg < NSEG - 1) xn = base[SL];

    // ---- geometric coefficient recurrences ----
    const float dti     = 1.0f / (float)TT;
    const float ti_base = (float)(seg * SL + 1) * dti;
    const float df      = P.f_start - P.f_inf;
    float ef = exp2f(P.log2K_invTd * ti_base);            // exp2(g*ti), ti = ti_base
    const float cf = exp2f(P.log2K_invTd * dti);          // per-step factor
    float ew = __expf(-(ti_base - P.w_offset) * P.inv_w_T);   // exp(-z), sigmoid = 1/(1+ew)
    const float cw = __expf(-dti * P.inv_w_T);

    // ---- 64-step local scan + transition composition ----
    float y1 = 0.0f, y2 = 0.0f, q3 = 0.0f;
    float al = 1.0f, be = 0.0f, ga = 0.0f, de = 0.0f, ws = 0.0f;
    #pragma unroll
    for (int k = 0; k < SL; k++) {
        float f  = fmaf(df, ef, P.f_inf);
        ef *= cf;
        float r  = __builtin_amdgcn_rcpf(f + P.c);
        float b  = f * r;                 // (a+1)/2 = f/(f+c)
        float m  = (P.c - f) * r;         // -a
        float p  = b * (1.0f + m);
        float w  = __builtin_amdgcn_rcpf(1.0f + ew);
        ew *= cw;
        if (seg == NSEG - 1 && k == SL - 1) { m = 0.0f; b = 0.0f; p = 0.0f; w = 0.0f; } // t=8192 pad

        float x  = (k < SL - 1) ? e[k + 1] : xn;
        float u  = b * (x + e[k]);                              // b*(x_t + x_{t-1})
        float y2n = fmaf(m, y2, fmaf(p, y1, b * u));            // m*y2 + p*y1 + b*u
        y1 = fmaf(m, y1, u);
        y2 = y2n;
        q3 = fmaf(w, y2n, q3);                                  // local acc

        float nal = m * al;
        float nbe = fmaf(p, al, m * be);
        de = fmaf(w * m, al, de);
        ga = fmaf(w, nbe, ga);
        al = nal; be = nbe;
        ws += w;
    }
    float q1 = y1, q2 = y2;

    // ---- in-wave composition tree: lane 0 ends with the half-row map ----
    #pragma unroll
    for (int o = 1; o < 64; o <<= 1) {
        float al2 = __shfl_down(al, o);
        float be2 = __shfl_down(be, o);
        float ga2 = __shfl_down(ga, o);
        float de2 = __shfl_down(de, o);
        float q12 = __shfl_down(q1, o);
        float q22 = __shfl_down(q2, o);
        float q32 = __shfl_down(q3, o);
        float ws2 = __shfl_down(ws, o);
        // T <- T2 (later) ∘ T (earlier)
        float nal = al2 * al;
        float nbe = fmaf(be2, al, al2 * be);
        float nga = fmaf(ga2, al, fmaf(de2, be, ga));
        float nde = fmaf(de2, al, de);
        float nq1 = fmaf(al2, q1, q12);
        float nq2 = fmaf(be2, q1, fmaf(al2, q2, q22));
        float nq3 = fmaf(ga2, q1, fmaf(de2, q2, q3 + q32));
        al = nal; be = nbe; ga = nga; de = nde;
        q1 = nq1; q2 = nq2; q3 = nq3; ws += ws2;
    }

    // ---- cross-wave (2 halves) combine per row ----
    __shared__ float sred[4][8];   // per wave: al,be,ga,de,q1,q2,q3,ws
    __shared__ float sx0[2];       // per local row: X[row][0]
    if (lane == 0) {
        sred[wid][0] = al; sred[wid][1] = be; sred[wid][2] = ga; sred[wid][3] = de;
        sred[wid][4] = q1; sred[wid][5] = q2; sred[wid][6] = q3; sred[wid][7] = ws;
        if (half == 0) sx0[rloc] = e[0];     // seg 0 starts at X[row][0]
    }
    __syncthreads();

    if (tid < 2) {
        int r = tid;
        const float* E = sred[2 * r + 0];    // earlier half (segments 0..63)
        const float* L = sred[2 * r + 1];    // later half (segments 64..127)
        float alE = E[0], beE = E[1], gaE = E[2], deE = E[3];
        float q1E = E[4], q2E = E[5], q3E = E[6];
        float gaL = L[2], deL = L[3], q3L = L[6];
        // acc row of T_L ∘ T_E applied to s0 = (x0, x0, w0*x0), plus q-feeds:
        float ga_f = fmaf(gaL, alE, fmaf(deL, beE, gaE));
        float de_f = fmaf(deL, alE, deE);
        float q3_f = fmaf(gaL, q1E, fmaf(deL, q2E, q3E + q3L));
        float x0 = sx0[r];
        float w0 = sigmoid_dev((0.0f - P.w_offset) * P.inv_w_T);
        float sumw = E[7] + L[7] + w0;
        float accf = fmaf(ga_f + de_f + w0, x0, q3_f);
        out[(blockIdx.x << 1) + r] = accf / sumw;
    }
}

extern "C" void kernel_launch(void* const* d_in, const int* in_sizes, int n_in,
                              void* d_out, int out_size, void* d_ws, size_t ws_size,
                              hipStream_t stream) {
    const float* X        = (const float*)d_in[0];
    const int*   Fp       = (const int*)d_in[1];
    const float* p_fstart = (const float*)d_in[2];
    const float* p_finf   = (const float*)d_in[3];
    const float* p_fdecay = (const float*)d_in[4];
    const float* p_fT     = (const float*)d_in[5];
    const float* p_woff   = (const float*)d_in[6];
    const float* p_wT     = (const float*)d_in[7];
    float* out = (float*)d_out;

    fused_kernel<<<BB / 2, 256, 0, stream>>>(X, Fp, p_fstart, p_finf, p_fdecay,
                                             p_fT, p_woff, p_wT, out);
}